// Round 14
// baseline (57.418 us; speedup 1.0000x reference)
//
#include <hip/hip_runtime.h>
#include <hip/hip_bf16.h>

#define BN 16
#define EN 128
#define HN 4
#define HCN 32
#define NN 1024
#define POSN 3969  // (2*32-1)*(2*32-1)

typedef short short8 __attribute__((ext_vector_type(8)));
typedef float f32x4 __attribute__((ext_vector_type(4)));

#define MFMA16(a, b, c) __builtin_amdgcn_mfma_f32_16x16x32_bf16((a), (b), (c), 0, 0, 0)

union Frag {
  short8 s8;
  uint2 u2[2];
  unsigned int u[4];
  unsigned short us[8];
};

__device__ __forceinline__ unsigned short bfbits(float x) {
  union { __hip_bfloat16 h; unsigned short u; } c;
  c.h = __float2bfloat16(x);
  return c.u;
}

__device__ __forceinline__ unsigned int pk2(float lo, float hi) {
  union { __hip_bfloat162 h2; unsigned int u; } c;
  c.h2 = __float22bfloat162_rn(make_float2(lo, hi));
  return c.u;
}

// ---------------------------------------------------------------------------
// Kernel 1 (fused, flat grid 965) — r11 verbatim:
//   blocks 0..767:  QKV conv via MFMA (inline W frags).
//   blocks 768..956: compact bias table [h][dy31 63][dxi 3][lane 64][4].
//   blocks 957..964: Wu hi/lo split frag tables.
// ---------------------------------------------------------------------------
__global__ __launch_bounds__(256) void conv_prep_kernel(
    const float* __restrict__ x,
    const float* __restrict__ Wk, const float* __restrict__ bk, __hip_bfloat16* __restrict__ kb,
    const float* __restrict__ Wq, const float* __restrict__ bq, __hip_bfloat16* __restrict__ qb,
    const float* __restrict__ Wv, const float* __restrict__ bv, __hip_bfloat16* __restrict__ vb,
    const float* __restrict__ Wu, const float* __restrict__ pos,
    unsigned short* __restrict__ bias, Frag* __restrict__ whitab, Frag* __restrict__ wlotab)
{
  const int bid = blockIdx.x, t = threadIdx.x;

  if (bid >= 768) {
    if (bid < 957) {
      const int gid = (bid - 768) * 256 + t;     // < 48384
      const int l = gid & 63;
      const int t2 = gid >> 6;
      const int dxi = t2 % 3;
      const int dy31 = (t2 / 3) % 63;
      const int h = t2 / 189;
      const int rowk0 = (l >> 4) * 4, colq = l & 15;
      const float log2e = 1.4426950408889634f;
      unsigned int bits[4];
#pragma unroll
      for (int j = 0; j < 4; ++j) {
        const int dx = (dxi - 1) * 16 + rowk0 + j - colq + 31;
        bits[j] = (unsigned int)bfbits(pos[h * POSN + dy31 * 63 + dx] * log2e);
      }
      uint2 o;
      o.x = bits[0] | (bits[1] << 16);
      o.y = bits[2] | (bits[3] << 16);
      *(uint2*)(bias + (size_t)gid * 4) = o;
    } else {
      const int fid = (bid - 957) * 256 + t;   // < 2048
      const int ot = fid >> 8, ks = (fid >> 6) & 3, l = fid & 63;
      const int o = ot * 16 + (l & 15), lq = l >> 4;
      const float* wp = Wu + (size_t)o * EN + ks * 32 + lq * 4;
      float4 wa = *(const float4*)wp;
      float4 wb2 = *(const float4*)(wp + 16);
      float v[8] = {wa.x, wa.y, wa.z, wa.w, wb2.x, wb2.y, wb2.z, wb2.w};
      unsigned short hb[8]; float lf[8];
#pragma unroll
      for (int e = 0; e < 8; ++e) {
        __hip_bfloat16 hh = __float2bfloat16(v[e]);
        union { __hip_bfloat16 h; unsigned short u; } c; c.h = hh;
        hb[e] = c.u;
        lf[e] = v[e] - __bfloat162float(hh);
      }
      Frag fh, fl;
#pragma unroll
      for (int e = 0; e < 4; ++e)
        fh.u[e] = hb[2 * e] | ((unsigned int)hb[2 * e + 1] << 16);
      fl.u[0] = pk2(lf[0], lf[1]); fl.u[1] = pk2(lf[2], lf[3]);
      fl.u[2] = pk2(lf[4], lf[5]); fl.u[3] = pk2(lf[6], lf[7]);
      whitab[fid] = fh;
      wlotab[fid] = fl;
    }
    return;
  }

  // ---- conv path ----
  const int z = bid >> 8;
  const float* W = (z == 0) ? Wk : (z == 1) ? Wq : Wv;
  const float* bias_v = (z == 0) ? bk : (z == 1) ? bq : bv;
  __hip_bfloat16* out = (z == 0) ? kb : (z == 1) ? qb : vb;

  const int n0 = (bid & 15) * 64;
  const int bb = (bid >> 4) & 15;
  const int w = t >> 6, l = t & 63;
  const int l15 = l & 15, lq = l >> 4;

  __shared__ unsigned short xs[64][132];   // [n][c]

  {
    const float* xb = x + (size_t)bb * EN * NN + n0;
    const int n = t & 63, cg = (t >> 6) * 4;
#pragma unroll
    for (int i = 0; i < 8; ++i) {
      const int cb = cg + i * 16;
      float a0 = xb[(size_t)(cb + 0) * NN + n];
      float a1 = xb[(size_t)(cb + 1) * NN + n];
      float a2 = xb[(size_t)(cb + 2) * NN + n];
      float a3 = xb[(size_t)(cb + 3) * NN + n];
      uint2 v; v.x = pk2(a0, a1); v.y = pk2(a2, a3);
      *(uint2*)&xs[n][cb] = v;
    }
  }

  Frag wf[2][4];
#pragma unroll
  for (int r = 0; r < 2; ++r) {
    const int o = (w * 2 + r) * 16 + l15;
#pragma unroll
    for (int ks = 0; ks < 4; ++ks) {
      const float* wp = W + (size_t)o * EN + ks * 32 + lq * 4;
      float4 wa = *(const float4*)wp;
      float4 wb2 = *(const float4*)(wp + 16);
      Frag f;
      f.u[0] = pk2(wa.x, wa.y);   f.u[1] = pk2(wa.z, wa.w);
      f.u[2] = pk2(wb2.x, wb2.y); f.u[3] = pk2(wb2.z, wb2.w);
      wf[r][ks] = f;
    }
  }
  __syncthreads();

  f32x4 acc[2][4];
#pragma unroll
  for (int r = 0; r < 2; ++r)
#pragma unroll
    for (int nt = 0; nt < 4; ++nt) acc[r][nt] = 0.f;

#pragma unroll
  for (int ks = 0; ks < 4; ++ks) {
#pragma unroll
    for (int nt = 0; nt < 4; ++nt) {
      Frag xf;
      xf.u2[0] = *(const uint2*)&xs[nt * 16 + l15][ks * 32 + lq * 4];
      xf.u2[1] = *(const uint2*)&xs[nt * 16 + l15][ks * 32 + lq * 4 + 16];
      if (z < 2) {
        acc[0][nt] = MFMA16(wf[0][ks].s8, xf.s8, acc[0][nt]);
        acc[1][nt] = MFMA16(wf[1][ks].s8, xf.s8, acc[1][nt]);
      } else {
        acc[0][nt] = MFMA16(xf.s8, wf[0][ks].s8, acc[0][nt]);
        acc[1][nt] = MFMA16(xf.s8, wf[1][ks].s8, acc[1][nt]);
      }
    }
  }

  if (z < 2) {
#pragma unroll
    for (int r = 0; r < 2; ++r) {
      const int ob = (w * 2 + r) * 16 + lq * 4;
      const int hh = ob >> 5;
      const int pofs = hh * 32 + ((ob >> 2) & 3) * 8 + ((ob & 16) ? 4 : 0);
      float4 b4 = *(const float4*)(bias_v + ob);
#pragma unroll
      for (int nt = 0; nt < 4; ++nt) {
        const int n = n0 + nt * 16 + l15;
        f32x4 a = acc[r][nt];
        uint2 o2;
        o2.x = pk2(a[0] + b4.x, a[1] + b4.y);
        o2.y = pk2(a[2] + b4.z, a[3] + b4.w);
        *(uint2*)(out + (size_t)(bb * NN + n) * 128 + pofs) = o2;
      }
    }
  } else {
#pragma unroll
    for (int r = 0; r < 2; ++r) {
      const int o = (w * 2 + r) * 16 + l15;
      const int c = o & 31, hh = o >> 5;
      const float bsc = bias_v[o];
#pragma unroll
      for (int nt = 0; nt < 4; ++nt) {
        const int nb = n0 + nt * 16 + lq * 4;
        const int kbk = nb >> 5, k32 = nb & 31;
        const int pofs = ((k32 >> 2) & 3) * 8 + ((k32 & 16) ? 4 : 0);
        f32x4 a = acc[r][nt];
        uint2 o2;
        o2.x = pk2(a[0] + bsc, a[1] + bsc);
        o2.y = pk2(a[2] + bsc, a[3] + bsc);
        *(uint2*)(out + ((size_t)((bb * 4 + hh) * 32 + c) * 32 + kbk) * 32 + pofs) = o2;
      }
    }
  }
}

// ---------------------------------------------------------------------------
// Attention (r11 main loop verbatim): k-split=2, 128-k chunks, reg-prefetch
// dbuf, setprio, l via ones-MFMA. ONLY change vs r11: epilogue stores partial
// O as bf16 in kperm-frag layout Opb[s*16+b][n][128perm] (one 16B store/nt).
// ---------------------------------------------------------------------------
__global__ __launch_bounds__(256, 4) void attn_mfma_kernel(
    const __hip_bfloat16* __restrict__ kp,     // kperm[b][n][h][32]
    const __hip_bfloat16* __restrict__ qp,     // qperm[b][n][h][32]
    const __hip_bfloat16* __restrict__ vp,     // vperm[b][h][c][kb][32]
    const unsigned short* __restrict__ bias,   // [h][63][3][64][4]
    __hip_bfloat16* __restrict__ Opb,          // [s*16+b][n][128perm] bf16
    float* __restrict__ lp)                    // [s][b][h][n] fp32 partial
{
  const int bx = blockIdx.x;
  const int qi = bx & 7, s = bx >> 3;
  const int h = blockIdx.y, b = blockIdx.z;
  const int t = threadIdx.x, w = t >> 6, l = t & 63;
  const int l15 = l & 15, lq = l >> 4;

  __shared__ Frag Kf[2][8][64];
  __shared__ Frag Vf[2][8][64];

  const __hip_bfloat16* kBase = kp + (size_t)b * 131072 + h * 32 + (size_t)l15 * 128 + lq * 8;
  const __hip_bfloat16* vBase = vp + (size_t)((b * 4 + h) * 32 + l15) * 1024 + lq * 8;
  const unsigned short* biasB = bias + (size_t)h * 48384 + l * 4;

#define KADDR(CHG, KT) ((const Frag*)(kBase + (size_t)((CHG) * 128 + (KT) * 16) * 128))
#define VADDR(CHG, SL) ((const Frag*)(vBase + (size_t)((SL) >> 2) * 16384 + ((CHG) * 4 + ((SL) & 3)) * 32))

  const int qt0 = qi * 8 + w * 2;
  Frag qf[2];
  qf[0] = *(const Frag*)(qp + (size_t)(b * 1024 + (qt0 + 0) * 16 + l15) * 128 + h * 32 + lq * 8);
  qf[1] = *(const Frag*)(qp + (size_t)(b * 1024 + (qt0 + 1) * 16 + l15) * 128 + h * 32 + lq * 8);
  const int qy[2] = {(qt0 + 0) >> 1, (qt0 + 1) >> 1};
  const int qx1[2] = {(qt0 + 0) & 1, (qt0 + 1) & 1};

  // stage chunk 0 (wave w stages K ktiles {w, w+4}, V slots {w, w+4})
  {
    const int chg = s * 4;
    Kf[0][w][l]     = *KADDR(chg, w);
    Kf[0][w + 4][l] = *KADDR(chg, w + 4);
    Vf[0][w][l]     = *VADDR(chg, w);
    Vf[0][w + 4][l] = *VADDR(chg, w + 4);
  }
  __syncthreads();

  f32x4 O[2][2];   // [mt][nt]
#pragma unroll
  for (int mt = 0; mt < 2; ++mt)
#pragma unroll
    for (int nt = 0; nt < 2; ++nt) O[mt][nt] = 0.f;
  f32x4 Lacc[2]; Lacc[0] = 0.f; Lacc[1] = 0.f;

  Frag ones;
  ones.u[0] = 0x3F803F80u; ones.u[1] = 0x3F803F80u;
  ones.u[2] = 0x3F803F80u; ones.u[3] = 0x3F803F80u;

  const float SCALE2 = 0.17677669529663687f * 1.4426950408889634f;  // hc^-.5 * log2e

  for (int c4 = 0; c4 < 4; ++c4) {
    const int buf = c4 & 1;
    const int chg = s * 4 + c4;

    Frag kn[2], vn[2];
    if (c4 < 3) {
      kn[0] = *KADDR(chg + 1, w);
      kn[1] = *KADDR(chg + 1, w + 4);
      vn[0] = *VADDR(chg + 1, w);
      vn[1] = *VADDR(chg + 1, w + 4);
    }

#pragma unroll
    for (int hh2 = 0; hh2 < 2; ++hh2) {
      short8 ka[4], va[4];
#pragma unroll
      for (int kt = 0; kt < 4; ++kt) ka[kt] = Kf[buf][hh2 * 4 + kt][l].s8;
#pragma unroll
      for (int mt = 0; mt < 2; ++mt)
#pragma unroll
        for (int kh = 0; kh < 2; ++kh)
          va[mt * 2 + kh] = Vf[buf][mt * 4 + hh2 * 2 + kh][l].s8;

#pragma unroll
      for (int nt = 0; nt < 2; ++nt) {
        uint2 bw[4];
#pragma unroll
        for (int kt = 0; kt < 4; ++kt) {
          const int ktg = chg * 8 + hh2 * 4 + kt;
          const int off = ((ktg >> 1) - qy[nt] + 31) * 768 + ((ktg & 1) - qx1[nt] + 1) * 256;
          bw[kt] = *(const uint2*)(biasB + off);
        }

        __builtin_amdgcn_s_setprio(1);
        f32x4 S[4];
#pragma unroll
        for (int kt = 0; kt < 4; ++kt) {
          f32x4 z = 0.f;
          S[kt] = MFMA16(ka[kt], qf[nt].s8, z);
        }
        __builtin_amdgcn_s_setprio(0);

        Frag B0, B1;
#pragma unroll
        for (int kt = 0; kt < 4; ++kt) {
          const float b0 = __uint_as_float(bw[kt].x << 16);
          const float b1 = __uint_as_float(bw[kt].x & 0xffff0000u);
          const float b2 = __uint_as_float(bw[kt].y << 16);
          const float b3 = __uint_as_float(bw[kt].y & 0xffff0000u);
          float p0 = exp2f(fmaf(S[kt][0], SCALE2, b0));
          float p1 = exp2f(fmaf(S[kt][1], SCALE2, b1));
          float p2 = exp2f(fmaf(S[kt][2], SCALE2, b2));
          float p3 = exp2f(fmaf(S[kt][3], SCALE2, b3));
          unsigned int lo = pk2(p0, p1), hi = pk2(p2, p3);
          if (kt < 2) { B0.u[kt * 2] = lo; B0.u[kt * 2 + 1] = hi; }
          else        { B1.u[(kt - 2) * 2] = lo; B1.u[(kt - 2) * 2 + 1] = hi; }
        }

        __builtin_amdgcn_s_setprio(1);
        O[0][nt] = MFMA16(va[0], B0.s8, O[0][nt]);
        O[0][nt] = MFMA16(va[1], B1.s8, O[0][nt]);
        O[1][nt] = MFMA16(va[2], B0.s8, O[1][nt]);
        O[1][nt] = MFMA16(va[3], B1.s8, O[1][nt]);
        Lacc[nt] = MFMA16(ones.s8, B0.s8, Lacc[nt]);
        Lacc[nt] = MFMA16(ones.s8, B1.s8, Lacc[nt]);
        __builtin_amdgcn_s_setprio(0);
      }
    }

    if (c4 < 3) {
      Kf[buf ^ 1][w][l]     = kn[0];
      Kf[buf ^ 1][w + 4][l] = kn[1];
      Vf[buf ^ 1][w][l]     = vn[0];
      Vf[buf ^ 1][w + 4][l] = vn[1];
      __syncthreads();
    }
  }
#undef KADDR
#undef VADDR

  if (lq == 0) {
#pragma unroll
    for (int nt = 0; nt < 2; ++nt)
      lp[((size_t)(s * 16 + b) * 4 + h) * 1024 + (qt0 + nt) * 16 + l15] = Lacc[nt][0];
  }

  // bf16 kperm-frag store: position h*32 + lq*8 + mt*4 + j holds
  // O[c = mt*16 + lq*4 + j][n]; one 16B store per nt.
  __hip_bfloat16* obb = Opb + ((size_t)(s * 16 + b) * 1024) * 128 + h * 32 + lq * 8;
#pragma unroll
  for (int nt = 0; nt < 2; ++nt) {
    const int n = (qt0 + nt) * 16 + l15;
    Frag f;
    f.u[0] = pk2(O[0][nt][0], O[0][nt][1]);
    f.u[1] = pk2(O[0][nt][2], O[0][nt][3]);
    f.u[2] = pk2(O[1][nt][0], O[1][nt][1]);
    f.u[3] = pk2(O[1][nt][2], O[1][nt][3]);
    *(Frag*)(obb + (size_t)n * 128) = f;
  }
}

// ---------------------------------------------------------------------------
// Final conv, LDS-free (r8, verified): A-frags straight from Opb, both
// k-split partials accumulate into the same acc (conv is linear), per-head
// normalize folded into the A-fragment, bf16x3 via Wu hi/lo tables.
// ---------------------------------------------------------------------------
__global__ __launch_bounds__(256, 2) void conv_final_mfma(
    const __hip_bfloat16* __restrict__ Opb,  // [s*16+b][n][128perm]
    const float* __restrict__ lp,            // [s][b][h][n]
    const Frag* __restrict__ whitab, const Frag* __restrict__ wlotab,
    const float* __restrict__ bu, float* __restrict__ out)
{
  const int n0 = blockIdx.x * 32;
  const int bb = blockIdx.y;
  const int t = threadIdx.x, w = t >> 6, l = t & 63;
  const int l15 = l & 15, lq = l >> 4;

  __shared__ float rls[4][32];
  if (t < 128) {
    const int h = t >> 5, nl = t & 31;
    const float l0 = lp[((size_t)(0 * 16 + bb) * 4 + h) * 1024 + n0 + nl];
    const float l1 = lp[((size_t)(1 * 16 + bb) * 4 + h) * 1024 + n0 + nl];
    rls[h][nl] = 1.0f / (l0 + l1);
  }

  Frag whi[2][4], wlo[2][4];
#pragma unroll
  for (int r = 0; r < 2; ++r)
#pragma unroll
    for (int ks = 0; ks < 4; ++ks) {
      const int idx = (((w * 2 + r) * 4) + ks) * 64 + l;
      whi[r][ks] = whitab[idx];
      wlo[r][ks] = wlotab[idx];
    }
  __syncthreads();

  f32x4 acc[2][2];
#pragma unroll
  for (int r = 0; r < 2; ++r)
#pragma unroll
    for (int nt = 0; nt < 2; ++nt) acc[r][nt] = 0.f;

#pragma unroll
  for (int s = 0; s < 2; ++s) {
#pragma unroll
    for (int h = 0; h < 4; ++h) {
      Frag a2[2];
#pragma unroll
      for (int nt = 0; nt < 2; ++nt) {
        const int n = n0 + nt * 16 + l15;
        Frag af = *(const Frag*)(Opb + ((size_t)((s * 16 + bb) * 1024 + n)) * 128 + h * 32 + lq * 8);
        const float sc = rls[h][nt * 16 + l15];
        Frag as;
#pragma unroll
        for (int e = 0; e < 4; ++e) {
          const float f0 = __uint_as_float((unsigned int)af.us[2 * e] << 16) * sc;
          const float f1 = __uint_as_float((unsigned int)af.us[2 * e + 1] << 16) * sc;
          as.u[e] = pk2(f0, f1);
        }
        a2[nt] = as;
      }
#pragma unroll
      for (int r = 0; r < 2; ++r)
#pragma unroll
        for (int nt = 0; nt < 2; ++nt) {
          acc[r][nt] = MFMA16(a2[nt].s8, whi[r][h].s8, acc[r][nt]);
          acc[r][nt] = MFMA16(a2[nt].s8, wlo[r][h].s8, acc[r][nt]);
        }
    }
  }

#pragma unroll
  for (int r = 0; r < 2; ++r) {
    const int o = (w * 2 + r) * 16 + l15;
    const float bo = bu[o];
#pragma unroll
    for (int nt = 0; nt < 2; ++nt) {
      const int nb = n0 + nt * 16 + lq * 4;
      f32x4 a = acc[r][nt];
      float4 res = make_float4(a[0] + bo, a[1] + bo, a[2] + bo, a[3] + bo);
      *(float4*)(out + ((size_t)bb * EN + o) * NN + nb) = res;
    }
  }
}

// ---------------------------------------------------------------------------
extern "C" void kernel_launch(void* const* d_in, const int* in_sizes, int n_in,
                              void* d_out, int out_size, void* d_ws, size_t ws_size,
                              hipStream_t stream)
{
  const float* x   = (const float*)d_in[0];
  const float* Wk  = (const float*)d_in[1];
  const float* bk  = (const float*)d_in[2];
  const float* Wq  = (const float*)d_in[3];
  const float* bq  = (const float*)d_in[4];
  const float* Wv  = (const float*)d_in[5];
  const float* bv  = (const float*)d_in[6];
  const float* Wu  = (const float*)d_in[7];
  const float* bu  = (const float*)d_in[8];
  const float* pos = (const float*)d_in[9];

  char* ws = (char*)d_ws;
  __hip_bfloat16* kb = (__hip_bfloat16*)(ws);                        // 4 MB kperm
  __hip_bfloat16* qb = (__hip_bfloat16*)(ws + (size_t)4194304);      // 4 MB qperm
  __hip_bfloat16* vb = (__hip_bfloat16*)(ws + (size_t)8388608);      // 4 MB vperm
  unsigned short* bias = (unsigned short*)(ws + (size_t)12582912);   // 387 KB
  Frag* whitab = (Frag*)(ws + (size_t)13068288);                     // 32 KB
  Frag* wlotab = (Frag*)(ws + (size_t)13101056);                     // 32 KB
  float* lp = (float*)(ws + (size_t)13133824);                       // 512 KB [2][b][h][n]
  __hip_bfloat16* Opb = (__hip_bfloat16*)(ws + (size_t)13658112);    // 8 MB bf16 frag layout

  conv_prep_kernel<<<965, 256, 0, stream>>>(x, Wk, bk, kb, Wq, bq, qb, Wv, bv, vb,
                                            Wu, pos, bias, whitab, wlotab);

  dim3 g2(16, HN, BN);
  attn_mfma_kernel<<<g2, 256, 0, stream>>>(kb, qb, vb, bias, Opb, lp);

  dim3 g3(32, BN);
  conv_final_mfma<<<g3, 256, 0, stream>>>(Opb, lp, whitab, wlotab, bu, (float*)d_out);
}

// Round 15
// 56.498 us; speedup vs baseline: 1.0163x; 1.0163x over previous
//
#include <hip/hip_runtime.h>
#include <hip/hip_bf16.h>

#define BN 16
#define EN 128
#define HN 4
#define HCN 32
#define NN 1024
#define POSN 3969  // (2*32-1)*(2*32-1)

typedef short short8 __attribute__((ext_vector_type(8)));
typedef float f32x4 __attribute__((ext_vector_type(4)));

#define MFMA16(a, b, c) __builtin_amdgcn_mfma_f32_16x16x32_bf16((a), (b), (c), 0, 0, 0)

union Frag {
  short8 s8;
  uint2 u2[2];
  unsigned int u[4];
  unsigned short us[8];
};

__device__ __forceinline__ unsigned short bfbits(float x) {
  union { __hip_bfloat16 h; unsigned short u; } c;
  c.h = __float2bfloat16(x);
  return c.u;
}

__device__ __forceinline__ unsigned int pk2(float lo, float hi) {
  union { __hip_bfloat162 h2; unsigned int u; } c;
  c.h2 = __float22bfloat162_rn(make_float2(lo, hi));
  return c.u;
}

// ---------------------------------------------------------------------------
// Kernel 1 (fused, flat grid 965) — r11 verbatim (measured best, 56.6 us):
//   blocks 0..767:  QKV conv via MFMA (inline W frags).
//   blocks 768..956: compact bias table [h][dy31 63][dxi 3][lane 64][4].
//   blocks 957..964: Wu hi/lo split frag tables.
// ---------------------------------------------------------------------------
__global__ __launch_bounds__(256) void conv_prep_kernel(
    const float* __restrict__ x,
    const float* __restrict__ Wk, const float* __restrict__ bk, __hip_bfloat16* __restrict__ kb,
    const float* __restrict__ Wq, const float* __restrict__ bq, __hip_bfloat16* __restrict__ qb,
    const float* __restrict__ Wv, const float* __restrict__ bv, __hip_bfloat16* __restrict__ vb,
    const float* __restrict__ Wu, const float* __restrict__ pos,
    unsigned short* __restrict__ bias, Frag* __restrict__ whitab, Frag* __restrict__ wlotab)
{
  const int bid = blockIdx.x, t = threadIdx.x;

  if (bid >= 768) {
    if (bid < 957) {
      const int gid = (bid - 768) * 256 + t;     // < 48384
      const int l = gid & 63;
      const int t2 = gid >> 6;
      const int dxi = t2 % 3;
      const int dy31 = (t2 / 3) % 63;
      const int h = t2 / 189;
      const int rowk0 = (l >> 4) * 4, colq = l & 15;
      const float log2e = 1.4426950408889634f;
      unsigned int bits[4];
#pragma unroll
      for (int j = 0; j < 4; ++j) {
        const int dx = (dxi - 1) * 16 + rowk0 + j - colq + 31;
        bits[j] = (unsigned int)bfbits(pos[h * POSN + dy31 * 63 + dx] * log2e);
      }
      uint2 o;
      o.x = bits[0] | (bits[1] << 16);
      o.y = bits[2] | (bits[3] << 16);
      *(uint2*)(bias + (size_t)gid * 4) = o;
    } else {
      const int fid = (bid - 957) * 256 + t;   // < 2048
      const int ot = fid >> 8, ks = (fid >> 6) & 3, l = fid & 63;
      const int o = ot * 16 + (l & 15), lq = l >> 4;
      const float* wp = Wu + (size_t)o * EN + ks * 32 + lq * 4;
      float4 wa = *(const float4*)wp;
      float4 wb2 = *(const float4*)(wp + 16);
      float v[8] = {wa.x, wa.y, wa.z, wa.w, wb2.x, wb2.y, wb2.z, wb2.w};
      unsigned short hb[8]; float lf[8];
#pragma unroll
      for (int e = 0; e < 8; ++e) {
        __hip_bfloat16 hh = __float2bfloat16(v[e]);
        union { __hip_bfloat16 h; unsigned short u; } c; c.h = hh;
        hb[e] = c.u;
        lf[e] = v[e] - __bfloat162float(hh);
      }
      Frag fh, fl;
#pragma unroll
      for (int e = 0; e < 4; ++e)
        fh.u[e] = hb[2 * e] | ((unsigned int)hb[2 * e + 1] << 16);
      fl.u[0] = pk2(lf[0], lf[1]); fl.u[1] = pk2(lf[2], lf[3]);
      fl.u[2] = pk2(lf[4], lf[5]); fl.u[3] = pk2(lf[6], lf[7]);
      whitab[fid] = fh;
      wlotab[fid] = fl;
    }
    return;
  }

  // ---- conv path ----
  const int z = bid >> 8;
  const float* W = (z == 0) ? Wk : (z == 1) ? Wq : Wv;
  const float* bias_v = (z == 0) ? bk : (z == 1) ? bq : bv;
  __hip_bfloat16* out = (z == 0) ? kb : (z == 1) ? qb : vb;

  const int n0 = (bid & 15) * 64;
  const int bb = (bid >> 4) & 15;
  const int w = t >> 6, l = t & 63;
  const int l15 = l & 15, lq = l >> 4;

  __shared__ unsigned short xs[64][132];   // [n][c]

  {
    const float* xb = x + (size_t)bb * EN * NN + n0;
    const int n = t & 63, cg = (t >> 6) * 4;
#pragma unroll
    for (int i = 0; i < 8; ++i) {
      const int cb = cg + i * 16;
      float a0 = xb[(size_t)(cb + 0) * NN + n];
      float a1 = xb[(size_t)(cb + 1) * NN + n];
      float a2 = xb[(size_t)(cb + 2) * NN + n];
      float a3 = xb[(size_t)(cb + 3) * NN + n];
      uint2 v; v.x = pk2(a0, a1); v.y = pk2(a2, a3);
      *(uint2*)&xs[n][cb] = v;
    }
  }

  Frag wf[2][4];
#pragma unroll
  for (int r = 0; r < 2; ++r) {
    const int o = (w * 2 + r) * 16 + l15;
#pragma unroll
    for (int ks = 0; ks < 4; ++ks) {
      const float* wp = W + (size_t)o * EN + ks * 32 + lq * 4;
      float4 wa = *(const float4*)wp;
      float4 wb2 = *(const float4*)(wp + 16);
      Frag f;
      f.u[0] = pk2(wa.x, wa.y);   f.u[1] = pk2(wa.z, wa.w);
      f.u[2] = pk2(wb2.x, wb2.y); f.u[3] = pk2(wb2.z, wb2.w);
      wf[r][ks] = f;
    }
  }
  __syncthreads();

  f32x4 acc[2][4];
#pragma unroll
  for (int r = 0; r < 2; ++r)
#pragma unroll
    for (int nt = 0; nt < 4; ++nt) acc[r][nt] = 0.f;

#pragma unroll
  for (int ks = 0; ks < 4; ++ks) {
#pragma unroll
    for (int nt = 0; nt < 4; ++nt) {
      Frag xf;
      xf.u2[0] = *(const uint2*)&xs[nt * 16 + l15][ks * 32 + lq * 4];
      xf.u2[1] = *(const uint2*)&xs[nt * 16 + l15][ks * 32 + lq * 4 + 16];
      if (z < 2) {
        acc[0][nt] = MFMA16(wf[0][ks].s8, xf.s8, acc[0][nt]);
        acc[1][nt] = MFMA16(wf[1][ks].s8, xf.s8, acc[1][nt]);
      } else {
        acc[0][nt] = MFMA16(xf.s8, wf[0][ks].s8, acc[0][nt]);
        acc[1][nt] = MFMA16(xf.s8, wf[1][ks].s8, acc[1][nt]);
      }
    }
  }

  if (z < 2) {
#pragma unroll
    for (int r = 0; r < 2; ++r) {
      const int ob = (w * 2 + r) * 16 + lq * 4;
      const int hh = ob >> 5;
      const int pofs = hh * 32 + ((ob >> 2) & 3) * 8 + ((ob & 16) ? 4 : 0);
      float4 b4 = *(const float4*)(bias_v + ob);
#pragma unroll
      for (int nt = 0; nt < 4; ++nt) {
        const int n = n0 + nt * 16 + l15;
        f32x4 a = acc[r][nt];
        uint2 o2;
        o2.x = pk2(a[0] + b4.x, a[1] + b4.y);
        o2.y = pk2(a[2] + b4.z, a[3] + b4.w);
        *(uint2*)(out + (size_t)(bb * NN + n) * 128 + pofs) = o2;
      }
    }
  } else {
#pragma unroll
    for (int r = 0; r < 2; ++r) {
      const int o = (w * 2 + r) * 16 + l15;
      const int c = o & 31, hh = o >> 5;
      const float bsc = bias_v[o];
#pragma unroll
      for (int nt = 0; nt < 4; ++nt) {
        const int nb = n0 + nt * 16 + lq * 4;
        const int kbk = nb >> 5, k32 = nb & 31;
        const int pofs = ((k32 >> 2) & 3) * 8 + ((k32 & 16) ? 4 : 0);
        f32x4 a = acc[r][nt];
        uint2 o2;
        o2.x = pk2(a[0] + bsc, a[1] + bsc);
        o2.y = pk2(a[2] + bsc, a[3] + bsc);
        *(uint2*)(out + ((size_t)((bb * 4 + hh) * 32 + c) * 32 + kbk) * 32 + pofs) = o2;
      }
    }
  }
}

// ---------------------------------------------------------------------------
// Attention (r11 verbatim, measured-best): k-split=2, 128-k chunks (4
// barriers), reg-prefetch dbuf, setprio around MFMA clusters, l via
// ones-MFMA. grid (8 qi x 2 s, h, b) = 1024 blocks, 4 waves, 32 KB LDS.
// Writes partial fp32 O and partial l; conv_final combines.
// ---------------------------------------------------------------------------
__global__ __launch_bounds__(256, 4) void attn_mfma_kernel(
    const __hip_bfloat16* __restrict__ kp,     // kperm[b][n][h][32]
    const __hip_bfloat16* __restrict__ qp,     // qperm[b][n][h][32]
    const __hip_bfloat16* __restrict__ vp,     // vperm[b][h][c][kb][32]
    const unsigned short* __restrict__ bias,   // [h][63][3][64][4]
    float* __restrict__ Op,                    // [s][b][e][n] fp32 partial
    float* __restrict__ lp)                    // [s][b][h][n] fp32 partial
{
  const int bx = blockIdx.x;
  const int qi = bx & 7, s = bx >> 3;
  const int h = blockIdx.y, b = blockIdx.z;
  const int t = threadIdx.x, w = t >> 6, l = t & 63;
  const int l15 = l & 15, lq = l >> 4;

  __shared__ Frag Kf[2][8][64];
  __shared__ Frag Vf[2][8][64];

  const __hip_bfloat16* kBase = kp + (size_t)b * 131072 + h * 32 + (size_t)l15 * 128 + lq * 8;
  const __hip_bfloat16* vBase = vp + (size_t)((b * 4 + h) * 32 + l15) * 1024 + lq * 8;
  const unsigned short* biasB = bias + (size_t)h * 48384 + l * 4;

#define KADDR(CHG, KT) ((const Frag*)(kBase + (size_t)((CHG) * 128 + (KT) * 16) * 128))
#define VADDR(CHG, SL) ((const Frag*)(vBase + (size_t)((SL) >> 2) * 16384 + ((CHG) * 4 + ((SL) & 3)) * 32))

  const int qt0 = qi * 8 + w * 2;
  Frag qf[2];
  qf[0] = *(const Frag*)(qp + (size_t)(b * 1024 + (qt0 + 0) * 16 + l15) * 128 + h * 32 + lq * 8);
  qf[1] = *(const Frag*)(qp + (size_t)(b * 1024 + (qt0 + 1) * 16 + l15) * 128 + h * 32 + lq * 8);
  const int qy[2] = {(qt0 + 0) >> 1, (qt0 + 1) >> 1};
  const int qx1[2] = {(qt0 + 0) & 1, (qt0 + 1) & 1};

  // stage chunk 0 (wave w stages K ktiles {w, w+4}, V slots {w, w+4})
  {
    const int chg = s * 4;
    Kf[0][w][l]     = *KADDR(chg, w);
    Kf[0][w + 4][l] = *KADDR(chg, w + 4);
    Vf[0][w][l]     = *VADDR(chg, w);
    Vf[0][w + 4][l] = *VADDR(chg, w + 4);
  }
  __syncthreads();

  f32x4 O[2][2];   // [mt][nt]
#pragma unroll
  for (int mt = 0; mt < 2; ++mt)
#pragma unroll
    for (int nt = 0; nt < 2; ++nt) O[mt][nt] = 0.f;
  f32x4 Lacc[2]; Lacc[0] = 0.f; Lacc[1] = 0.f;

  Frag ones;
  ones.u[0] = 0x3F803F80u; ones.u[1] = 0x3F803F80u;
  ones.u[2] = 0x3F803F80u; ones.u[3] = 0x3F803F80u;

  const float SCALE2 = 0.17677669529663687f * 1.4426950408889634f;  // hc^-.5 * log2e

  for (int c4 = 0; c4 < 4; ++c4) {
    const int buf = c4 & 1;
    const int chg = s * 4 + c4;

    Frag kn[2], vn[2];
    if (c4 < 3) {
      kn[0] = *KADDR(chg + 1, w);
      kn[1] = *KADDR(chg + 1, w + 4);
      vn[0] = *VADDR(chg + 1, w);
      vn[1] = *VADDR(chg + 1, w + 4);
    }

#pragma unroll
    for (int hh2 = 0; hh2 < 2; ++hh2) {
      short8 ka[4], va[4];
#pragma unroll
      for (int kt = 0; kt < 4; ++kt) ka[kt] = Kf[buf][hh2 * 4 + kt][l].s8;
#pragma unroll
      for (int mt = 0; mt < 2; ++mt)
#pragma unroll
        for (int kh = 0; kh < 2; ++kh)
          va[mt * 2 + kh] = Vf[buf][mt * 4 + hh2 * 2 + kh][l].s8;

#pragma unroll
      for (int nt = 0; nt < 2; ++nt) {
        uint2 bw[4];
#pragma unroll
        for (int kt = 0; kt < 4; ++kt) {
          const int ktg = chg * 8 + hh2 * 4 + kt;
          const int off = ((ktg >> 1) - qy[nt] + 31) * 768 + ((ktg & 1) - qx1[nt] + 1) * 256;
          bw[kt] = *(const uint2*)(biasB + off);
        }

        __builtin_amdgcn_s_setprio(1);
        f32x4 S[4];
#pragma unroll
        for (int kt = 0; kt < 4; ++kt) {
          f32x4 z = 0.f;
          S[kt] = MFMA16(ka[kt], qf[nt].s8, z);
        }
        __builtin_amdgcn_s_setprio(0);

        Frag B0, B1;
#pragma unroll
        for (int kt = 0; kt < 4; ++kt) {
          const float b0 = __uint_as_float(bw[kt].x << 16);
          const float b1 = __uint_as_float(bw[kt].x & 0xffff0000u);
          const float b2 = __uint_as_float(bw[kt].y << 16);
          const float b3 = __uint_as_float(bw[kt].y & 0xffff0000u);
          float p0 = exp2f(fmaf(S[kt][0], SCALE2, b0));
          float p1 = exp2f(fmaf(S[kt][1], SCALE2, b1));
          float p2 = exp2f(fmaf(S[kt][2], SCALE2, b2));
          float p3 = exp2f(fmaf(S[kt][3], SCALE2, b3));
          unsigned int lo = pk2(p0, p1), hi = pk2(p2, p3);
          if (kt < 2) { B0.u[kt * 2] = lo; B0.u[kt * 2 + 1] = hi; }
          else        { B1.u[(kt - 2) * 2] = lo; B1.u[(kt - 2) * 2 + 1] = hi; }
        }

        __builtin_amdgcn_s_setprio(1);
        O[0][nt] = MFMA16(va[0], B0.s8, O[0][nt]);
        O[0][nt] = MFMA16(va[1], B1.s8, O[0][nt]);
        O[1][nt] = MFMA16(va[2], B0.s8, O[1][nt]);
        O[1][nt] = MFMA16(va[3], B1.s8, O[1][nt]);
        Lacc[nt] = MFMA16(ones.s8, B0.s8, Lacc[nt]);
        Lacc[nt] = MFMA16(ones.s8, B1.s8, Lacc[nt]);
        __builtin_amdgcn_s_setprio(0);
      }
    }

    if (c4 < 3) {
      Kf[buf ^ 1][w][l]     = kn[0];
      Kf[buf ^ 1][w + 4][l] = kn[1];
      Vf[buf ^ 1][w][l]     = vn[0];
      Vf[buf ^ 1][w + 4][l] = vn[1];
      __syncthreads();
    }
  }
#undef KADDR
#undef VADDR

  if (lq == 0) {
#pragma unroll
    for (int nt = 0; nt < 2; ++nt)
      lp[((size_t)(s * 16 + b) * 4 + h) * 1024 + (qt0 + nt) * 16 + l15] = Lacc[nt][0];
  }

  float* ob = Op + (size_t)s * 2097152 + ((size_t)b * EN + h * HCN) * NN;
#pragma unroll
  for (int mt = 0; mt < 2; ++mt)
#pragma unroll
    for (int nt = 0; nt < 2; ++nt)
#pragma unroll
      for (int j = 0; j < 4; ++j)
        ob[(size_t)(mt * 16 + lq * 4 + j) * NN + (qt0 + nt) * 16 + l15] = O[mt][nt][j];
}

// ---------------------------------------------------------------------------
// Final conv (r11 verbatim): bf16x3 split MFMA with W frags from tables,
// fused k-split combine + normalize: a[c][n] = (O0+O1)/(l0+l1).
// ---------------------------------------------------------------------------
__global__ __launch_bounds__(256) void conv_final_mfma(
    const float* __restrict__ Op,   // [2][b][e][n]
    const float* __restrict__ lp,   // [2][b][h][n]
    const Frag* __restrict__ whitab, const Frag* __restrict__ wlotab,
    const float* __restrict__ bu, float* __restrict__ out)
{
  const int n0 = blockIdx.x * 32;
  const int bb = blockIdx.y;
  const int t = threadIdx.x, w = t >> 6, l = t & 63;
  const int l15 = l & 15, lq = l >> 4;

  __shared__ unsigned short ahi[32][132];
  __shared__ unsigned short alo[32][132];

  {
    const float* O0 = Op + (size_t)bb * (EN * NN) + n0;
    const float* O1 = O0 + 2097152;
    const float* l0 = lp + (size_t)bb * 4096 + n0;
    const float* l1 = l0 + 65536;
    const int n = t & 31, cg = (t >> 5) * 4;
#pragma unroll
    for (int i = 0; i < 4; ++i) {
      const int cb = cg + i * 32;   // h = i
      const float rl = 1.0f / (l0[i * 1024 + n] + l1[i * 1024 + n]);
      float a[4]; unsigned short hb[4]; float lf[4];
#pragma unroll
      for (int j = 0; j < 4; ++j) {
        a[j] = (O0[(size_t)(cb + j) * NN + n] + O1[(size_t)(cb + j) * NN + n]) * rl;
        __hip_bfloat16 hh = __float2bfloat16(a[j]);
        union { __hip_bfloat16 h; unsigned short u; } c; c.h = hh;
        hb[j] = c.u;
        lf[j] = a[j] - __bfloat162float(hh);
      }
      uint2 uh; uh.x = hb[0] | ((unsigned int)hb[1] << 16);
                uh.y = hb[2] | ((unsigned int)hb[3] << 16);
      uint2 ul; ul.x = pk2(lf[0], lf[1]); ul.y = pk2(lf[2], lf[3]);
      *(uint2*)&ahi[n][cb] = uh;
      *(uint2*)&alo[n][cb] = ul;
    }
  }

  Frag whi[2][4], wlo[2][4];
#pragma unroll
  for (int r = 0; r < 2; ++r)
#pragma unroll
    for (int ks = 0; ks < 4; ++ks) {
      const int idx = (((w * 2 + r) * 4) + ks) * 64 + l;
      whi[r][ks] = whitab[idx];
      wlo[r][ks] = wlotab[idx];
    }
  __syncthreads();

  f32x4 acc[2][2];
#pragma unroll
  for (int r = 0; r < 2; ++r)
#pragma unroll
    for (int nt = 0; nt < 2; ++nt) acc[r][nt] = 0.f;

#pragma unroll
  for (int ks = 0; ks < 4; ++ks) {
#pragma unroll
    for (int nt = 0; nt < 2; ++nt) {
      Frag ah, al;
      ah.u2[0] = *(const uint2*)&ahi[nt * 16 + l15][ks * 32 + lq * 4];
      ah.u2[1] = *(const uint2*)&ahi[nt * 16 + l15][ks * 32 + lq * 4 + 16];
      al.u2[0] = *(const uint2*)&alo[nt * 16 + l15][ks * 32 + lq * 4];
      al.u2[1] = *(const uint2*)&alo[nt * 16 + l15][ks * 32 + lq * 4 + 16];
#pragma unroll
      for (int r = 0; r < 2; ++r) {
        acc[r][nt] = MFMA16(ah.s8, whi[r][ks].s8, acc[r][nt]);
        acc[r][nt] = MFMA16(al.s8, whi[r][ks].s8, acc[r][nt]);
        acc[r][nt] = MFMA16(ah.s8, wlo[r][ks].s8, acc[r][nt]);
      }
    }
  }

#pragma unroll
  for (int r = 0; r < 2; ++r) {
    const int o = (w * 2 + r) * 16 + l15;
    const float bo = bu[o];
#pragma unroll
    for (int nt = 0; nt < 2; ++nt) {
      const int nb = n0 + nt * 16 + lq * 4;
      f32x4 a = acc[r][nt];
      float4 res = make_float4(a[0] + bo, a[1] + bo, a[2] + bo, a[3] + bo);
      *(float4*)(out + ((size_t)bb * EN + o) * NN + nb) = res;
    }
  }
}

// ---------------------------------------------------------------------------
extern "C" void kernel_launch(void* const* d_in, const int* in_sizes, int n_in,
                              void* d_out, int out_size, void* d_ws, size_t ws_size,
                              hipStream_t stream)
{
  const float* x   = (const float*)d_in[0];
  const float* Wk  = (const float*)d_in[1];
  const float* bk  = (const float*)d_in[2];
  const float* Wq  = (const float*)d_in[3];
  const float* bq  = (const float*)d_in[4];
  const float* Wv  = (const float*)d_in[5];
  const float* bv  = (const float*)d_in[6];
  const float* Wu  = (const float*)d_in[7];
  const float* bu  = (const float*)d_in[8];
  const float* pos = (const float*)d_in[9];

  char* ws = (char*)d_ws;
  __hip_bfloat16* kb = (__hip_bfloat16*)(ws);                        // 4 MB kperm
  __hip_bfloat16* qb = (__hip_bfloat16*)(ws + (size_t)4194304);      // 4 MB qperm
  __hip_bfloat16* vb = (__hip_bfloat16*)(ws + (size_t)8388608);      // 4 MB vperm
  unsigned short* bias = (unsigned short*)(ws + (size_t)12582912);   // 387 KB
  Frag* whitab = (Frag*)(ws + (size_t)13068288);                     // 32 KB
  Frag* wlotab = (Frag*)(ws + (size_t)13101056);                     // 32 KB
  float* lp = (float*)(ws + (size_t)13133824);                       // 512 KB [2][b][h][n]
  float* Op = (float*)(ws + (size_t)13658112);                       // 16 MB [2][b][e][n]

  conv_prep_kernel<<<965, 256, 0, stream>>>(x, Wk, bk, kb, Wq, bq, qb, Wv, bv, vb,
                                            Wu, pos, bias, whitab, wlotab);

  dim3 g2(16, HN, BN);
  attn_mfma_kernel<<<g2, 256, 0, stream>>>(kb, qb, vb, bias, Op, lp);

  dim3 g3(32, BN);
  conv_final_mfma<<<g3, 256, 0, stream>>>(Op, lp, whitab, wlotab, bu, (float*)d_out);
}